// Round 1
// baseline (273.594 us; speedup 1.0000x reference)
//
#include <hip/hip_runtime.h>

#define NN 50000
#define NE 600000
#define D 128
#define BN_EPS 1e-5f

// ---------------- degree count ----------------
__global__ void count_deg(const int* __restrict__ row, int* __restrict__ deg) {
    int e = blockIdx.x * blockDim.x + threadIdx.x;
    if (e < NE) atomicAdd(&deg[row[e]], 1);
}

// ---------------- two-level exclusive scan ----------------
__global__ void scan_block(const int* __restrict__ in, int* __restrict__ out,
                           int* __restrict__ bsum, int n) {
    __shared__ int s[256];
    int i = blockIdx.x * 256 + threadIdx.x;
    int v = (i < n) ? in[i] : 0;
    s[threadIdx.x] = v;
    __syncthreads();
    for (int d = 1; d < 256; d <<= 1) {
        int t = (threadIdx.x >= d) ? s[threadIdx.x - d] : 0;
        __syncthreads();
        s[threadIdx.x] += t;
        __syncthreads();
    }
    if (i < n) out[i] = s[threadIdx.x] - v;       // exclusive
    if (threadIdx.x == 255 && bsum) bsum[blockIdx.x] = s[255];
}

__global__ void scan_add(int* __restrict__ offs, const int* __restrict__ boff,
                         int* __restrict__ cursor, int n) {
    int i = blockIdx.x * 256 + threadIdx.x;
    if (i < n) {
        int v = offs[i] + boff[blockIdx.x];
        offs[i] = v;
        cursor[i] = v;
    }
}

// ---------------- CSR fill ----------------
__global__ void fill_adj(const int* __restrict__ row, const int* __restrict__ col,
                         int* __restrict__ cursor, int* __restrict__ adj) {
    int e = blockIdx.x * blockDim.x + threadIdx.x;
    if (e < NE) {
        int slot = atomicAdd(&cursor[row[e]], 1);
        adj[slot] = col[e];
    }
}

// ---------------- gather: h = x + agg/deg  (one wave per node) ----------------
__global__ __launch_bounds__(256) void gather_h(const float* __restrict__ x,
                                                const int* __restrict__ offs,
                                                const int* __restrict__ deg,
                                                const int* __restrict__ adj,
                                                float* __restrict__ h) {
    int gw = (blockIdx.x * blockDim.x + threadIdx.x) >> 6;   // global wave id = node
    int lane = threadIdx.x & 63;
    if (gw >= NN) return;
    int start = offs[gw];
    int dg = deg[gw];
    float a0 = 0.f, a1 = 0.f;
    for (int j = 0; j < dg; j++) {
        int nb = adj[start + j];
        const float* xr = x + (size_t)nb * D;
        a0 += xr[lane];
        a1 += xr[lane + 64];
    }
    float inv = (dg > 0) ? (1.0f / (float)dg) : 0.f;
    const float* xn = x + (size_t)gw * D;
    h[(size_t)gw * D + lane]      = xn[lane]      + a0 * inv;
    h[(size_t)gw * D + lane + 64] = xn[lane + 64] + a1 * inv;
}

// ---------------- GEMM (y = h @ W^T + b) fused with BN partial sums ----------------
// block: 256 threads, 16 nodes. thread t: local row r = t>>4, og = t&15,
// outputs o = og + 16k, k=0..7. sW stride 129 -> 16 concurrent reads hit 16 banks.
#define WS 129
__global__ __launch_bounds__(256) void gemm_bn(const float* __restrict__ h,
                                               const float* __restrict__ W,
                                               const float* __restrict__ bias,
                                               float* __restrict__ y,
                                               float* __restrict__ colsum,
                                               float* __restrict__ colsq) {
    __shared__ float sW[D * WS];        // 66048 B
    __shared__ float sh[16 * WS];       // 8256 B
    __shared__ float lsum[D], lsq[D];   // 1024 B
    int t = threadIdx.x;
    int node0 = blockIdx.x * 16;

    for (int i = t; i < D * D; i += 256)
        sW[(i >> 7) * WS + (i & 127)] = W[i];
    for (int i = t; i < 16 * D; i += 256)
        sh[(i >> 7) * WS + (i & 127)] = h[(size_t)node0 * D + i];
    if (t < D) { lsum[t] = 0.f; lsq[t] = 0.f; }
    __syncthreads();

    int r = t >> 4, og = t & 15;
    float acc[8];
    #pragma unroll
    for (int k = 0; k < 8; k++) acc[k] = bias[og + 16 * k];

    const float* hrow = &sh[r * WS];
    const float* wb = &sW[og * WS];
    #pragma unroll 4
    for (int d = 0; d < D; d++) {
        float hv = hrow[d];
        #pragma unroll
        for (int k = 0; k < 8; k++)
            acc[k] += hv * wb[k * (16 * WS) + d];
    }

    size_t base = (size_t)(node0 + r) * D;
    #pragma unroll
    for (int k = 0; k < 8; k++) y[base + og + 16 * k] = acc[k];

    // reduce over the 4 rows sharing this og within the wave (lanes ^16, ^32)
    float s[8], q[8];
    #pragma unroll
    for (int k = 0; k < 8; k++) { s[k] = acc[k]; q[k] = acc[k] * acc[k]; }
    #pragma unroll
    for (int k = 0; k < 8; k++) {
        s[k] += __shfl_xor(s[k], 16);
        s[k] += __shfl_xor(s[k], 32);
        q[k] += __shfl_xor(q[k], 16);
        q[k] += __shfl_xor(q[k], 32);
    }
    if ((threadIdx.x & 63) < 16) {
        #pragma unroll
        for (int k = 0; k < 8; k++) {
            atomicAdd(&lsum[og + 16 * k], s[k]);
            atomicAdd(&lsq[og + 16 * k], q[k]);
        }
    }
    __syncthreads();
    if (t < D) {
        atomicAdd(&colsum[t], lsum[t]);
        atomicAdd(&colsq[t], lsq[t]);
    }
}

// ---------------- BN finalize ----------------
__global__ void bn_finalize(const float* __restrict__ colsum, const float* __restrict__ colsq,
                            const float* __restrict__ gamma, const float* __restrict__ beta,
                            float* __restrict__ scale, float* __restrict__ shift) {
    int d = threadIdx.x;
    if (d < D) {
        float mean = colsum[d] * (1.0f / NN);
        float var  = colsq[d] * (1.0f / NN) - mean * mean;
        float sc = gamma[d] * rsqrtf(var + BN_EPS);
        scale[d] = sc;
        shift[d] = beta[d] - mean * sc;
    }
}

// ---------------- BN apply + ReLU (in place on y/out) ----------------
__global__ __launch_bounds__(256) void bn_relu(float* __restrict__ y,
                                               const float* __restrict__ scale,
                                               const float* __restrict__ shift) {
    int i = blockIdx.x * blockDim.x + threadIdx.x;     // float4 index
    if (i < NN * D / 4) {
        float4 v = ((float4*)y)[i];
        int c = (i * 4) & 127;
        v.x = fmaxf(0.f, v.x * scale[c]     + shift[c]);
        v.y = fmaxf(0.f, v.y * scale[c + 1] + shift[c + 1]);
        v.z = fmaxf(0.f, v.z * scale[c + 2] + shift[c + 2]);
        v.w = fmaxf(0.f, v.w * scale[c + 3] + shift[c + 3]);
        ((float4*)y)[i] = v;
    }
}

extern "C" void kernel_launch(void* const* d_in, const int* in_sizes, int n_in,
                              void* d_out, int out_size, void* d_ws, size_t ws_size,
                              hipStream_t stream) {
    const float* x     = (const float*)d_in[0];
    const int*   edge  = (const int*)d_in[1];
    const float* W     = (const float*)d_in[2];
    const float* bias  = (const float*)d_in[3];
    const float* gamma = (const float*)d_in[4];
    const float* beta  = (const float*)d_in[5];
    float* out = (float*)d_out;

    const int* row = edge;        // edge_index[0] = destinations
    const int* col = edge + NE;   // edge_index[1] = sources

    char* w = (char*)d_ws;
    auto alloc = [&](size_t bytes) {
        char* p = w;
        w += (bytes + 255) & ~(size_t)255;
        return p;
    };
    int*   deg    = (int*)alloc((size_t)NN * 4);
    int*   offs   = (int*)alloc((size_t)NN * 4);
    int*   cursor = (int*)alloc((size_t)NN * 4);
    int*   bsum   = (int*)alloc(256 * 4);
    int*   boff   = (int*)alloc(256 * 4);
    int*   adj    = (int*)alloc((size_t)NE * 4);
    float* colsum = (float*)alloc(D * 4);
    float* colsq  = (float*)alloc(D * 4);
    float* scale  = (float*)alloc(D * 4);
    float* shiftb = (float*)alloc(D * 4);
    float* h      = (float*)alloc((size_t)NN * D * 4);

    hipMemsetAsync(deg, 0, (size_t)NN * 4, stream);
    hipMemsetAsync(colsum, 0, D * 4, stream);
    hipMemsetAsync(colsq, 0, D * 4, stream);

    int ebl = (NE + 255) / 256;
    int nb1 = (NN + 255) / 256;   // 196

    count_deg<<<ebl, 256, 0, stream>>>(row, deg);
    scan_block<<<nb1, 256, 0, stream>>>(deg, offs, bsum, NN);
    scan_block<<<1, 256, 0, stream>>>(bsum, boff, nullptr, nb1);
    scan_add<<<nb1, 256, 0, stream>>>(offs, boff, cursor, NN);
    fill_adj<<<ebl, 256, 0, stream>>>(row, col, cursor, adj);
    gather_h<<<(NN * 64 + 255) / 256, 256, 0, stream>>>(x, offs, deg, adj, h);
    gemm_bn<<<NN / 16, 256, 0, stream>>>(h, W, bias, out, colsum, colsq);
    bn_finalize<<<1, 128, 0, stream>>>(colsum, colsq, gamma, beta, scale, shiftb);
    bn_relu<<<(NN * D / 4 + 255) / 256, 256, 0, stream>>>(out, scale, shiftb);
}

// Round 3
// 169.746 us; speedup vs baseline: 1.6118x; 1.6118x over previous
//
#include <hip/hip_runtime.h>

#define NN 50000
#define NE 600000
#define D 128
#define BN_EPS 1e-5f

typedef __attribute__((ext_vector_type(8))) short bf16x8;
typedef __attribute__((ext_vector_type(4))) float f32x4;
typedef unsigned int uint;
typedef unsigned short ushort;

__device__ __forceinline__ ushort f2bf(float f) {
    uint u = __float_as_uint(f);
    uint r = (u + 0x7fffu + ((u >> 16) & 1u)) >> 16;   // round-to-nearest-even
    return (ushort)r;
}

// ---------------- x -> bf16 (one float2 per thread) ----------------
__global__ __launch_bounds__(256) void xcvt(const float* __restrict__ x, uint* __restrict__ xb) {
    int i = blockIdx.x * 256 + threadIdx.x;
    if (i < NN * (D / 2)) {
        float2 v = ((const float2*)x)[i];
        xb[i] = (uint)f2bf(v.x) | ((uint)f2bf(v.y) << 16);
    }
}

// ---------------- W -> bf16 ----------------
__global__ __launch_bounds__(256) void wcvt(const float* __restrict__ W, ushort* __restrict__ Wb) {
    int i = blockIdx.x * 256 + threadIdx.x;
    if (i < D * D) Wb[i] = f2bf(W[i]);
}

// ---------------- degree count ----------------
__global__ void count_deg(const int* __restrict__ row, int* __restrict__ deg) {
    int e = blockIdx.x * blockDim.x + threadIdx.x;
    if (e < NE) atomicAdd(&deg[row[e]], 1);
}

// ---------------- two-level exclusive scan ----------------
__global__ void scan_block(const int* __restrict__ in, int* __restrict__ out,
                           int* __restrict__ bsum, int n) {
    __shared__ int s[256];
    int i = blockIdx.x * 256 + threadIdx.x;
    int v = (i < n) ? in[i] : 0;
    s[threadIdx.x] = v;
    __syncthreads();
    for (int d = 1; d < 256; d <<= 1) {
        int t = (threadIdx.x >= d) ? s[threadIdx.x - d] : 0;
        __syncthreads();
        s[threadIdx.x] += t;
        __syncthreads();
    }
    if (i < n) out[i] = s[threadIdx.x] - v;       // exclusive
    if (threadIdx.x == 255 && bsum) bsum[blockIdx.x] = s[255];
}

__global__ void scan_add(int* __restrict__ offs, const int* __restrict__ boff,
                         int* __restrict__ cursor, int n) {
    int i = blockIdx.x * 256 + threadIdx.x;
    if (i < n) {
        int v = offs[i] + boff[blockIdx.x];
        offs[i] = v;
        cursor[i] = v;
    }
}

// ---------------- CSR fill ----------------
__global__ void fill_adj(const int* __restrict__ row, const int* __restrict__ col,
                         int* __restrict__ cursor, int* __restrict__ adj) {
    int e = blockIdx.x * blockDim.x + threadIdx.x;
    if (e < NE) {
        int slot = atomicAdd(&cursor[row[e]], 1);
        adj[slot] = col[e];
    }
}

// ---------------- gather: h = bf16(x + agg/deg), one wave per node ----------------
__global__ __launch_bounds__(256) void gather_h(const float* __restrict__ x,
                                                const uint* __restrict__ xb,
                                                const int* __restrict__ offs,
                                                const int* __restrict__ deg,
                                                const int* __restrict__ adj,
                                                uint* __restrict__ hb) {
    int gw = (blockIdx.x * blockDim.x + threadIdx.x) >> 6;   // node
    int lane = threadIdx.x & 63;
    if (gw >= NN) return;
    int start = offs[gw];
    int dg = deg[gw];
    float a0 = 0.f, a1 = 0.f;
    #pragma unroll 4
    for (int j = 0; j < dg; j++) {
        int nb = adj[start + j];
        uint v = xb[(size_t)nb * (D / 2) + lane];
        a0 += __uint_as_float(v << 16);
        a1 += __uint_as_float(v & 0xffff0000u);
    }
    float inv = (dg > 0) ? (1.0f / (float)dg) : 0.f;
    float2 xn = ((const float2*)x)[(size_t)gw * (D / 2) + lane];
    uint o = (uint)f2bf(xn.x + a0 * inv) | ((uint)f2bf(xn.y + a1 * inv) << 16);
    hb[(size_t)gw * (D / 2) + lane] = o;
}

// ---------------- MFMA GEMM (y = h @ W^T + b) fused with BN partial sums ----------
// 256 threads = 4 waves; wave w owns rows row0 = blk*64 + w*16, all 128 cols.
// A frag (16x32): lane holds h[row0 + (l&15)][kb*8 + j + ks*32], kb=lane>>4.
// B frag: lane holds W[col][same k]  (B = W^T, W row-major [out][in]).
// D: col = lane&15, row = (lane>>4)*4 + reg  (m89-verified layout).
__global__ __launch_bounds__(256) void gemm_bn2(const ushort* __restrict__ hb,
                                                const ushort* __restrict__ Wb,
                                                const float* __restrict__ bias,
                                                float* __restrict__ y,
                                                float* __restrict__ colsum,
                                                float* __restrict__ colsq) {
    __shared__ float lsum[D], lsq[D];
    int t = threadIdx.x;
    int lane = t & 63;
    int wv = t >> 6;
    if (t < D) { lsum[t] = 0.f; lsq[t] = 0.f; }
    __syncthreads();

    int row0 = blockIdx.x * 64 + wv * 16;
    int kb = lane >> 4;                       // 0..3
    int ar = row0 + (lane & 15);
    if (ar >= NN) ar = NN - 1;                // clamp loads; stores/stats masked

    const bf16x8* hrow = (const bf16x8*)(hb + (size_t)ar * D);
    bf16x8 a0 = hrow[0 * 4 + kb];
    bf16x8 a1 = hrow[1 * 4 + kb];
    bf16x8 a2 = hrow[2 * 4 + kb];
    bf16x8 a3 = hrow[3 * 4 + kb];

    int rbase = row0 + (lane >> 4) * 4;       // C rows this thread owns

    #pragma unroll
    for (int nt = 0; nt < 8; nt++) {
        int col = nt * 16 + (lane & 15);
        const bf16x8* wr = (const bf16x8*)(Wb + (size_t)col * D);
        bf16x8 b0 = wr[0 * 4 + kb];
        bf16x8 b1 = wr[1 * 4 + kb];
        bf16x8 b2 = wr[2 * 4 + kb];
        bf16x8 b3 = wr[3 * 4 + kb];

        float bv = bias[col];
        f32x4 acc = {bv, bv, bv, bv};
        acc = __builtin_amdgcn_mfma_f32_16x16x32_bf16(a0, b0, acc, 0, 0, 0);
        acc = __builtin_amdgcn_mfma_f32_16x16x32_bf16(a1, b1, acc, 0, 0, 0);
        acc = __builtin_amdgcn_mfma_f32_16x16x32_bf16(a2, b2, acc, 0, 0, 0);
        acc = __builtin_amdgcn_mfma_f32_16x16x32_bf16(a3, b3, acc, 0, 0, 0);

        float s = 0.f, q = 0.f;
        #pragma unroll
        for (int r = 0; r < 4; r++) {
            int rr = rbase + r;
            if (rr < NN) {
                y[(size_t)rr * D + col] = acc[r];
                s += acc[r];
                q += acc[r] * acc[r];
            }
        }
        s += __shfl_xor(s, 16); s += __shfl_xor(s, 32);
        q += __shfl_xor(q, 16); q += __shfl_xor(q, 32);
        if (lane < 16) {
            atomicAdd(&lsum[nt * 16 + lane], s);
            atomicAdd(&lsq[nt * 16 + lane], q);
        }
    }
    __syncthreads();
    if (t < D) {
        atomicAdd(&colsum[t], lsum[t]);
        atomicAdd(&colsq[t], lsq[t]);
    }
}

// ---------------- BN finalize ----------------
__global__ void bn_finalize(const float* __restrict__ colsum, const float* __restrict__ colsq,
                            const float* __restrict__ gamma, const float* __restrict__ beta,
                            float* __restrict__ scale, float* __restrict__ shift) {
    int d = threadIdx.x;
    if (d < D) {
        float mean = colsum[d] * (1.0f / NN);
        float var  = colsq[d] * (1.0f / NN) - mean * mean;
        float sc = gamma[d] * rsqrtf(var + BN_EPS);
        scale[d] = sc;
        shift[d] = beta[d] - mean * sc;
    }
}

// ---------------- BN apply + ReLU (in place on y/out) ----------------
__global__ __launch_bounds__(256) void bn_relu(float* __restrict__ y,
                                               const float* __restrict__ scale,
                                               const float* __restrict__ shift) {
    int i = blockIdx.x * blockDim.x + threadIdx.x;     // float4 index
    if (i < NN * D / 4) {
        float4 v = ((float4*)y)[i];
        int c = (i * 4) & 127;
        v.x = fmaxf(0.f, v.x * scale[c]     + shift[c]);
        v.y = fmaxf(0.f, v.y * scale[c + 1] + shift[c + 1]);
        v.z = fmaxf(0.f, v.z * scale[c + 2] + shift[c + 2]);
        v.w = fmaxf(0.f, v.w * scale[c + 3] + shift[c + 3]);
        ((float4*)y)[i] = v;
    }
}

extern "C" void kernel_launch(void* const* d_in, const int* in_sizes, int n_in,
                              void* d_out, int out_size, void* d_ws, size_t ws_size,
                              hipStream_t stream) {
    const float* x     = (const float*)d_in[0];
    const int*   edge  = (const int*)d_in[1];
    const float* W     = (const float*)d_in[2];
    const float* bias  = (const float*)d_in[3];
    const float* gamma = (const float*)d_in[4];
    const float* beta  = (const float*)d_in[5];
    float* out = (float*)d_out;

    const int* row = edge;        // edge_index[0] = destinations
    const int* col = edge + NE;   // edge_index[1] = sources

    char* w = (char*)d_ws;
    auto alloc = [&](size_t bytes) {
        char* p = w;
        w += (bytes + 255) & ~(size_t)255;
        return p;
    };
    int*    deg    = (int*)alloc((size_t)NN * 4);
    int*    offs   = (int*)alloc((size_t)NN * 4);
    int*    cursor = (int*)alloc((size_t)NN * 4);
    int*    bsum   = (int*)alloc(256 * 4);
    int*    boff   = (int*)alloc(256 * 4);
    int*    adj    = (int*)alloc((size_t)NE * 4);
    float*  colsum = (float*)alloc(D * 4);
    float*  colsq  = (float*)alloc(D * 4);
    float*  scale  = (float*)alloc(D * 4);
    float*  shiftb = (float*)alloc(D * 4);
    uint*   xb     = (uint*)alloc((size_t)NN * (D / 2) * 4);
    uint*   hb     = (uint*)alloc((size_t)NN * (D / 2) * 4);
    ushort* Wb     = (ushort*)alloc((size_t)D * D * 2);

    (void)hipMemsetAsync(deg, 0, (size_t)NN * 4, stream);
    (void)hipMemsetAsync(colsum, 0, D * 4, stream);
    (void)hipMemsetAsync(colsq, 0, D * 4, stream);

    int ebl = (NE + 255) / 256;
    int nb1 = (NN + 255) / 256;   // 196

    xcvt<<<(NN * (D / 2) + 255) / 256, 256, 0, stream>>>(x, xb);
    wcvt<<<(D * D + 255) / 256, 256, 0, stream>>>(W, Wb);
    count_deg<<<ebl, 256, 0, stream>>>(row, deg);
    scan_block<<<nb1, 256, 0, stream>>>(deg, offs, bsum, NN);
    scan_block<<<1, 256, 0, stream>>>(bsum, boff, nullptr, nb1);
    scan_add<<<nb1, 256, 0, stream>>>(offs, boff, cursor, NN);
    fill_adj<<<ebl, 256, 0, stream>>>(row, col, cursor, adj);
    gather_h<<<(NN * 64 + 255) / 256, 256, 0, stream>>>(x, xb, offs, deg, adj, hb);
    gemm_bn2<<<(NN + 63) / 64, 256, 0, stream>>>((const ushort*)hb, (const ushort*)Wb,
                                                 bias, out, colsum, colsq);
    bn_finalize<<<1, 128, 0, stream>>>(colsum, colsq, gamma, beta, scale, shiftb);
    bn_relu<<<(NN * D / 4 + 255) / 256, 256, 0, stream>>>(out, scale, shiftb);
}

// Round 4
// 157.787 us; speedup vs baseline: 1.7339x; 1.0758x over previous
//
#include <hip/hip_runtime.h>

#define NN 50000
#define NE 600000
#define D 128
#define BN_EPS 1e-5f

typedef __attribute__((ext_vector_type(8))) short bf16x8;
typedef __attribute__((ext_vector_type(4))) float f32x4;
typedef unsigned int uint;
typedef unsigned short ushort;

__device__ __forceinline__ ushort f2bf(float f) {
    uint u = __float_as_uint(f);
    uint r = (u + 0x7fffu + ((u >> 16) & 1u)) >> 16;   // round-to-nearest-even
    return (ushort)r;
}

// ---------------- prep: x->bf16, W->bf16, zero deg/colsum/colsq ----------------
// one kernel replaces 3 hipMemsetAsync fills (each ~40us as rocclr fillBuffer
// dispatches in the graph!) + xcvt + wcvt.
__global__ __launch_bounds__(256) void prep(const float* __restrict__ x,
                                            const float* __restrict__ W,
                                            uint* __restrict__ xb,
                                            ushort* __restrict__ Wb,
                                            int* __restrict__ deg,
                                            float* __restrict__ colsum,
                                            float* __restrict__ colsq) {
    int i = blockIdx.x * 256 + threadIdx.x;
    if (i < NN * (D / 2)) {
        float2 v = ((const float2*)x)[i];
        xb[i] = (uint)f2bf(v.x) | ((uint)f2bf(v.y) << 16);
    }
    if (i < D * D) Wb[i] = f2bf(W[i]);
    if (i < NN) deg[i] = 0;
    if (i < D) { colsum[i] = 0.f; colsq[i] = 0.f; }
}

// ---------------- degree count ----------------
__global__ void count_deg(const int* __restrict__ row, int* __restrict__ deg) {
    int e = blockIdx.x * blockDim.x + threadIdx.x;
    if (e < NE) atomicAdd(&deg[row[e]], 1);
}

// ---------------- two-level exclusive scan ----------------
__global__ void scan_block(const int* __restrict__ in, int* __restrict__ out,
                           int* __restrict__ bsum, int n) {
    __shared__ int s[256];
    int i = blockIdx.x * 256 + threadIdx.x;
    int v = (i < n) ? in[i] : 0;
    s[threadIdx.x] = v;
    __syncthreads();
    for (int d = 1; d < 256; d <<= 1) {
        int t = (threadIdx.x >= d) ? s[threadIdx.x - d] : 0;
        __syncthreads();
        s[threadIdx.x] += t;
        __syncthreads();
    }
    if (i < n) out[i] = s[threadIdx.x] - v;       // exclusive
    if (threadIdx.x == 255 && bsum) bsum[blockIdx.x] = s[255];
}

__global__ void scan_add(int* __restrict__ offs, const int* __restrict__ boff,
                         int* __restrict__ cursor, int n) {
    int i = blockIdx.x * 256 + threadIdx.x;
    if (i < n) {
        int v = offs[i] + boff[blockIdx.x];
        offs[i] = v;
        cursor[i] = v;
    }
}

// ---------------- CSR fill ----------------
__global__ void fill_adj(const int* __restrict__ row, const int* __restrict__ col,
                         int* __restrict__ cursor, int* __restrict__ adj) {
    int e = blockIdx.x * blockDim.x + threadIdx.x;
    if (e < NE) {
        int slot = atomicAdd(&cursor[row[e]], 1);
        adj[slot] = col[e];
    }
}

// ---------------- gather: h = bf16(x + agg/deg), one wave per node ----------------
__global__ __launch_bounds__(256) void gather_h(const float* __restrict__ x,
                                                const uint* __restrict__ xb,
                                                const int* __restrict__ offs,
                                                const int* __restrict__ deg,
                                                const int* __restrict__ adj,
                                                uint* __restrict__ hb) {
    int gw = (blockIdx.x * blockDim.x + threadIdx.x) >> 6;   // node
    int lane = threadIdx.x & 63;
    if (gw >= NN) return;
    int start = offs[gw];
    int dg = deg[gw];
    float a0 = 0.f, a1 = 0.f;
    #pragma unroll 4
    for (int j = 0; j < dg; j++) {
        int nb = adj[start + j];
        uint v = xb[(size_t)nb * (D / 2) + lane];
        a0 += __uint_as_float(v << 16);
        a1 += __uint_as_float(v & 0xffff0000u);
    }
    float inv = (dg > 0) ? (1.0f / (float)dg) : 0.f;
    float2 xn = ((const float2*)x)[(size_t)gw * (D / 2) + lane];
    uint o = (uint)f2bf(xn.x + a0 * inv) | ((uint)f2bf(xn.y + a1 * inv) << 16);
    hb[(size_t)gw * (D / 2) + lane] = o;
}

// ---------------- MFMA GEMM (y = h @ W^T + b) fused with BN partial sums ----------
// 256 threads = 4 waves; wave w owns rows row0 = blk*64 + w*16, all 128 cols.
// D layout: col = lane&15, row = (lane>>4)*4 + reg  (m89-verified).
__global__ __launch_bounds__(256) void gemm_bn2(const ushort* __restrict__ hb,
                                                const ushort* __restrict__ Wb,
                                                const float* __restrict__ bias,
                                                float* __restrict__ y,
                                                float* __restrict__ colsum,
                                                float* __restrict__ colsq) {
    __shared__ float lsum[D], lsq[D];
    int t = threadIdx.x;
    int lane = t & 63;
    int wv = t >> 6;
    if (t < D) { lsum[t] = 0.f; lsq[t] = 0.f; }
    __syncthreads();

    int row0 = blockIdx.x * 64 + wv * 16;
    int kb = lane >> 4;                       // 0..3
    int ar = row0 + (lane & 15);
    if (ar >= NN) ar = NN - 1;                // clamp loads; stores/stats masked

    const bf16x8* hrow = (const bf16x8*)(hb + (size_t)ar * D);
    bf16x8 a0 = hrow[0 * 4 + kb];
    bf16x8 a1 = hrow[1 * 4 + kb];
    bf16x8 a2 = hrow[2 * 4 + kb];
    bf16x8 a3 = hrow[3 * 4 + kb];

    int rbase = row0 + (lane >> 4) * 4;       // C rows this thread owns

    #pragma unroll
    for (int nt = 0; nt < 8; nt++) {
        int col = nt * 16 + (lane & 15);
        const bf16x8* wr = (const bf16x8*)(Wb + (size_t)col * D);
        bf16x8 b0 = wr[0 * 4 + kb];
        bf16x8 b1 = wr[1 * 4 + kb];
        bf16x8 b2 = wr[2 * 4 + kb];
        bf16x8 b3 = wr[3 * 4 + kb];

        float bv = bias[col];
        f32x4 acc = {bv, bv, bv, bv};
        acc = __builtin_amdgcn_mfma_f32_16x16x32_bf16(a0, b0, acc, 0, 0, 0);
        acc = __builtin_amdgcn_mfma_f32_16x16x32_bf16(a1, b1, acc, 0, 0, 0);
        acc = __builtin_amdgcn_mfma_f32_16x16x32_bf16(a2, b2, acc, 0, 0, 0);
        acc = __builtin_amdgcn_mfma_f32_16x16x32_bf16(a3, b3, acc, 0, 0, 0);

        float s = 0.f, q = 0.f;
        #pragma unroll
        for (int r = 0; r < 4; r++) {
            int rr = rbase + r;
            if (rr < NN) {
                y[(size_t)rr * D + col] = acc[r];
                s += acc[r];
                q += acc[r] * acc[r];
            }
        }
        s += __shfl_xor(s, 16); s += __shfl_xor(s, 32);
        q += __shfl_xor(q, 16); q += __shfl_xor(q, 32);
        if (lane < 16) {
            atomicAdd(&lsum[nt * 16 + lane], s);
            atomicAdd(&lsq[nt * 16 + lane], q);
        }
    }
    __syncthreads();
    if (t < D) {
        atomicAdd(&colsum[t], lsum[t]);
        atomicAdd(&colsq[t], lsq[t]);
    }
}

// ---------------- BN finalize + apply + ReLU (in place on y/out) ----------------
__global__ __launch_bounds__(256) void bn_relu(float* __restrict__ y,
                                               const float* __restrict__ colsum,
                                               const float* __restrict__ colsq,
                                               const float* __restrict__ gamma,
                                               const float* __restrict__ beta) {
    int i = blockIdx.x * blockDim.x + threadIdx.x;     // float4 index
    if (i >= NN * D / 4) return;
    int c = (i * 4) & 127;
    float4 v = ((float4*)y)[i];
    float* vp = (float*)&v;
    #pragma unroll
    for (int j = 0; j < 4; j++) {
        float mean = colsum[c + j] * (1.0f / NN);
        float var  = colsq[c + j] * (1.0f / NN) - mean * mean;
        float sc = gamma[c + j] * rsqrtf(var + BN_EPS);
        float sh = beta[c + j] - mean * sc;
        vp[j] = fmaxf(0.f, vp[j] * sc + sh);
    }
    ((float4*)y)[i] = v;
}

extern "C" void kernel_launch(void* const* d_in, const int* in_sizes, int n_in,
                              void* d_out, int out_size, void* d_ws, size_t ws_size,
                              hipStream_t stream) {
    const float* x     = (const float*)d_in[0];
    const int*   edge  = (const int*)d_in[1];
    const float* W     = (const float*)d_in[2];
    const float* bias  = (const float*)d_in[3];
    const float* gamma = (const float*)d_in[4];
    const float* beta  = (const float*)d_in[5];
    float* out = (float*)d_out;

    const int* row = edge;        // edge_index[0] = destinations
    const int* col = edge + NE;   // edge_index[1] = sources

    char* w = (char*)d_ws;
    auto alloc = [&](size_t bytes) {
        char* p = w;
        w += (bytes + 255) & ~(size_t)255;
        return p;
    };
    int*    deg    = (int*)alloc((size_t)NN * 4);
    int*    offs   = (int*)alloc((size_t)NN * 4);
    int*    cursor = (int*)alloc((size_t)NN * 4);
    int*    bsum   = (int*)alloc(256 * 4);
    int*    boff   = (int*)alloc(256 * 4);
    int*    adj    = (int*)alloc((size_t)NE * 4);
    float*  colsum = (float*)alloc(D * 4);
    float*  colsq  = (float*)alloc(D * 4);
    uint*   xb     = (uint*)alloc((size_t)NN * (D / 2) * 4);
    uint*   hb     = (uint*)alloc((size_t)NN * (D / 2) * 4);
    ushort* Wb     = (ushort*)alloc((size_t)D * D * 2);

    int ebl = (NE + 255) / 256;
    int nb1 = (NN + 255) / 256;   // 196

    prep<<<(NN * (D / 2) + 255) / 256, 256, 0, stream>>>(x, W, xb, Wb, deg, colsum, colsq);
    count_deg<<<ebl, 256, 0, stream>>>(row, deg);
    scan_block<<<nb1, 256, 0, stream>>>(deg, offs, bsum, NN);
    scan_block<<<1, 256, 0, stream>>>(bsum, boff, nullptr, nb1);
    scan_add<<<nb1, 256, 0, stream>>>(offs, boff, cursor, NN);
    fill_adj<<<ebl, 256, 0, stream>>>(row, col, cursor, adj);
    gather_h<<<(NN * 64 + 255) / 256, 256, 0, stream>>>(x, xb, offs, deg, adj, hb);
    gemm_bn2<<<(NN + 63) / 64, 256, 0, stream>>>((const ushort*)hb, (const ushort*)Wb,
                                                 bias, out, colsum, colsq);
    bn_relu<<<(NN * D / 4 + 255) / 256, 256, 0, stream>>>(out, colsum, colsq, gamma, beta);
}

// Round 5
// 154.194 us; speedup vs baseline: 1.7743x; 1.0233x over previous
//
#include <hip/hip_runtime.h>

#define NN 50000
#define NE 600000
#define D 128
#define BN_EPS 1e-5f

typedef __attribute__((ext_vector_type(8))) short bf16x8;
typedef __attribute__((ext_vector_type(4))) float f32x4;
typedef unsigned int uint;
typedef unsigned short ushort;

__device__ __forceinline__ ushort f2bf(float f) {
    uint u = __float_as_uint(f);
    uint r = (u + 0x7fffu + ((u >> 16) & 1u)) >> 16;   // round-to-nearest-even
    return (ushort)r;
}
__device__ __forceinline__ float bflo(uint v) { return __uint_as_float(v << 16); }
__device__ __forceinline__ float bfhi(uint v) { return __uint_as_float(v & 0xffff0000u); }

// ---------------- prep: x->bf16, W->bf16, zero deg/colsum/colsq ----------------
__global__ __launch_bounds__(256) void prep(const float* __restrict__ x,
                                            const float* __restrict__ W,
                                            uint* __restrict__ xb,
                                            ushort* __restrict__ Wb,
                                            int* __restrict__ deg,
                                            float* __restrict__ colsum,
                                            float* __restrict__ colsq) {
    int i = blockIdx.x * 256 + threadIdx.x;
    if (i < NN * (D / 2)) {
        float2 v = ((const float2*)x)[i];
        xb[i] = (uint)f2bf(v.x) | ((uint)f2bf(v.y) << 16);
    }
    if (i < D * D) Wb[i] = f2bf(W[i]);
    if (i < NN) deg[i] = 0;
    if (i < D) { colsum[i] = 0.f; colsq[i] = 0.f; }
}

// ---------------- degree count ----------------
__global__ void count_deg(const int* __restrict__ row, int* __restrict__ deg) {
    int e = blockIdx.x * blockDim.x + threadIdx.x;
    if (e < NE) atomicAdd(&deg[row[e]], 1);
}

// ---------------- block-level exclusive scan ----------------
__global__ void scan_block(const int* __restrict__ in, int* __restrict__ out,
                           int* __restrict__ bsum, int n) {
    __shared__ int s[256];
    int i = blockIdx.x * 256 + threadIdx.x;
    int v = (i < n) ? in[i] : 0;
    s[threadIdx.x] = v;
    __syncthreads();
    for (int d = 1; d < 256; d <<= 1) {
        int t = (threadIdx.x >= d) ? s[threadIdx.x - d] : 0;
        __syncthreads();
        s[threadIdx.x] += t;
        __syncthreads();
    }
    if (i < n) out[i] = s[threadIdx.x] - v;       // exclusive
    if (threadIdx.x == 255 && bsum) bsum[blockIdx.x] = s[255];
}

// ---------------- add block offsets; each block reduces bsum[0..b) itself ------
__global__ __launch_bounds__(256) void scan_add2(int* __restrict__ offs,
                                                 const int* __restrict__ bsum,
                                                 int* __restrict__ cursor, int nb) {
    __shared__ int ls[4];
    int t = threadIdx.x, b = blockIdx.x;
    int v = (t < b && t < nb) ? bsum[t] : 0;      // nb <= 256
    #pragma unroll
    for (int d = 1; d < 64; d <<= 1) v += __shfl_xor(v, d);
    if ((t & 63) == 0) ls[t >> 6] = v;
    __syncthreads();
    int boffb = ls[0] + ls[1] + ls[2] + ls[3];
    int i = b * 256 + t;
    if (i < NN) {
        int o = offs[i] + boffb;
        offs[i] = o;
        cursor[i] = o;
    }
}

// ---------------- CSR fill ----------------
__global__ void fill_adj(const int* __restrict__ row, const int* __restrict__ col,
                         int* __restrict__ cursor, int* __restrict__ adj) {
    int e = blockIdx.x * blockDim.x + threadIdx.x;
    if (e < NE) {
        int slot = atomicAdd(&cursor[row[e]], 1);
        adj[slot] = col[e];
    }
}

// ---------------- gather: h = bf16(xb + agg/deg), one wave per node ------------
__global__ __launch_bounds__(256) void gather_h(const uint* __restrict__ xb,
                                                const int* __restrict__ offs,
                                                const int* __restrict__ deg,
                                                const int* __restrict__ adj,
                                                uint* __restrict__ hb) {
    int gw = (blockIdx.x * blockDim.x + threadIdx.x) >> 6;   // node
    int lane = threadIdx.x & 63;
    if (gw >= NN) return;
    int start = offs[gw];
    int dg = deg[gw];
    float a0 = 0.f, a1 = 0.f;
    #pragma unroll 4
    for (int j = 0; j < dg; j++) {
        int nb = adj[start + j];
        uint v = xb[(size_t)nb * (D / 2) + lane];
        a0 += bflo(v);
        a1 += bfhi(v);
    }
    float inv = (dg > 0) ? (1.0f / (float)dg) : 0.f;
    uint xs = xb[(size_t)gw * (D / 2) + lane];
    uint o = (uint)f2bf(bflo(xs) + a0 * inv) | ((uint)f2bf(bfhi(xs) + a1 * inv) << 16);
    hb[(size_t)gw * (D / 2) + lane] = o;
}

// ---------------- MFMA GEMM (y = h @ W^T + b) fused with BN partial sums ----------
// 256 threads = 4 waves; wave w owns rows row0 = blk*64 + w*16, all 128 cols.
// D layout: col = lane&15, row = (lane>>4)*4 + reg  (m89-verified).
// y written as bf16 to halve round-trip traffic.
__global__ __launch_bounds__(256) void gemm_bn2(const ushort* __restrict__ hb,
                                                const ushort* __restrict__ Wb,
                                                const float* __restrict__ bias,
                                                ushort* __restrict__ yb,
                                                float* __restrict__ colsum,
                                                float* __restrict__ colsq) {
    __shared__ float lsum[D], lsq[D];
    int t = threadIdx.x;
    int lane = t & 63;
    int wv = t >> 6;
    if (t < D) { lsum[t] = 0.f; lsq[t] = 0.f; }
    __syncthreads();

    int row0 = blockIdx.x * 64 + wv * 16;
    int kb = lane >> 4;                       // 0..3
    int ar = row0 + (lane & 15);
    if (ar >= NN) ar = NN - 1;                // clamp loads; stores/stats masked

    const bf16x8* hrow = (const bf16x8*)(hb + (size_t)ar * D);
    bf16x8 a0 = hrow[0 * 4 + kb];
    bf16x8 a1 = hrow[1 * 4 + kb];
    bf16x8 a2 = hrow[2 * 4 + kb];
    bf16x8 a3 = hrow[3 * 4 + kb];

    int rbase = row0 + (lane >> 4) * 4;       // C rows this thread owns

    #pragma unroll
    for (int nt = 0; nt < 8; nt++) {
        int col = nt * 16 + (lane & 15);
        const bf16x8* wr = (const bf16x8*)(Wb + (size_t)col * D);
        bf16x8 b0 = wr[0 * 4 + kb];
        bf16x8 b1 = wr[1 * 4 + kb];
        bf16x8 b2 = wr[2 * 4 + kb];
        bf16x8 b3 = wr[3 * 4 + kb];

        float bv = bias[col];
        f32x4 acc = {bv, bv, bv, bv};
        acc = __builtin_amdgcn_mfma_f32_16x16x32_bf16(a0, b0, acc, 0, 0, 0);
        acc = __builtin_amdgcn_mfma_f32_16x16x32_bf16(a1, b1, acc, 0, 0, 0);
        acc = __builtin_amdgcn_mfma_f32_16x16x32_bf16(a2, b2, acc, 0, 0, 0);
        acc = __builtin_amdgcn_mfma_f32_16x16x32_bf16(a3, b3, acc, 0, 0, 0);

        float s = 0.f, q = 0.f;
        #pragma unroll
        for (int r = 0; r < 4; r++) {
            int rr = rbase + r;
            if (rr < NN) {
                yb[(size_t)rr * D + col] = f2bf(acc[r]);
                s += acc[r];
                q += acc[r] * acc[r];
            }
        }
        s += __shfl_xor(s, 16); s += __shfl_xor(s, 32);
        q += __shfl_xor(q, 16); q += __shfl_xor(q, 32);
        if (lane < 16) {
            atomicAdd(&lsum[nt * 16 + lane], s);
            atomicAdd(&lsq[nt * 16 + lane], q);
        }
    }
    __syncthreads();
    if (t < D) {
        atomicAdd(&colsum[t], lsum[t]);
        atomicAdd(&colsq[t], lsq[t]);
    }
}

// ---------------- BN finalize + apply + ReLU (bf16 y -> f32 out) ----------------
__global__ __launch_bounds__(256) void bn_relu(const uint* __restrict__ yb,
                                               float* __restrict__ out,
                                               const float* __restrict__ colsum,
                                               const float* __restrict__ colsq,
                                               const float* __restrict__ gamma,
                                               const float* __restrict__ beta) {
    int i = blockIdx.x * blockDim.x + threadIdx.x;     // float4 / uint2 index
    if (i >= NN * D / 4) return;
    uint2 yv = ((const uint2*)yb)[i];
    float yf[4] = {bflo(yv.x), bfhi(yv.x), bflo(yv.y), bfhi(yv.y)};
    int c = (i * 4) & 127;
    float4 v;
    float* vp = (float*)&v;
    #pragma unroll
    for (int j = 0; j < 4; j++) {
        float mean = colsum[c + j] * (1.0f / NN);
        float var  = colsq[c + j] * (1.0f / NN) - mean * mean;
        float sc = gamma[c + j] * rsqrtf(var + BN_EPS);
        float sh = beta[c + j] - mean * sc;
        vp[j] = fmaxf(0.f, yf[j] * sc + sh);
    }
    ((float4*)out)[i] = v;
}

extern "C" void kernel_launch(void* const* d_in, const int* in_sizes, int n_in,
                              void* d_out, int out_size, void* d_ws, size_t ws_size,
                              hipStream_t stream) {
    const float* x     = (const float*)d_in[0];
    const int*   edge  = (const int*)d_in[1];
    const float* W     = (const float*)d_in[2];
    const float* bias  = (const float*)d_in[3];
    const float* gamma = (const float*)d_in[4];
    const float* beta  = (const float*)d_in[5];
    float* out = (float*)d_out;

    const int* row = edge;        // edge_index[0] = destinations
    const int* col = edge + NE;   // edge_index[1] = sources

    char* w = (char*)d_ws;
    auto alloc = [&](size_t bytes) {
        char* p = w;
        w += (bytes + 255) & ~(size_t)255;
        return p;
    };
    int*    deg    = (int*)alloc((size_t)NN * 4);
    int*    offs   = (int*)alloc((size_t)NN * 4);
    int*    cursor = (int*)alloc((size_t)NN * 4);
    int*    bsum   = (int*)alloc(256 * 4);
    int*    adj    = (int*)alloc((size_t)NE * 4);
    float*  colsum = (float*)alloc(D * 4);
    float*  colsq  = (float*)alloc(D * 4);
    uint*   xb     = (uint*)alloc((size_t)NN * (D / 2) * 4);
    uint*   hb     = (uint*)alloc((size_t)NN * (D / 2) * 4);
    uint*   yb     = (uint*)alloc((size_t)NN * (D / 2) * 4);
    ushort* Wb     = (ushort*)alloc((size_t)D * D * 2);

    int ebl = (NE + 255) / 256;
    int nb1 = (NN + 255) / 256;   // 196

    prep<<<(NN * (D / 2) + 255) / 256, 256, 0, stream>>>(x, W, xb, Wb, deg, colsum, colsq);
    count_deg<<<ebl, 256, 0, stream>>>(row, deg);
    scan_block<<<nb1, 256, 0, stream>>>(deg, offs, bsum, NN);
    scan_add2<<<nb1, 256, 0, stream>>>(offs, bsum, cursor, nb1);
    fill_adj<<<ebl, 256, 0, stream>>>(row, col, cursor, adj);
    gather_h<<<(NN * 64 + 255) / 256, 256, 0, stream>>>(xb, offs, deg, adj, hb);
    gemm_bn2<<<(NN + 63) / 64, 256, 0, stream>>>((const ushort*)hb, (const ushort*)Wb,
                                                 bias, (ushort*)yb, colsum, colsq);
    bn_relu<<<(NN * D / 4 + 255) / 256, 256, 0, stream>>>(yb, out, colsum, colsq, gamma, beta);
}